// Round 13
// baseline (296.811 us; speedup 1.0000x reference)
//
#include <hip/hip_runtime.h>
#include <hip/hip_bf16.h>

#define NN   30000
#define EE   960000
#define IND  2048
#define NEMB 64
#define NH1  32
#define NH2  16
#define NET  64
#define NB   16

typedef __bf16 bf8 __attribute__((ext_vector_type(8)));
typedef __bf16 bf4 __attribute__((ext_vector_type(4)));
typedef __bf16 bf2 __attribute__((ext_vector_type(2)));
typedef float  f4  __attribute__((ext_vector_type(4)));

#define AS3 __attribute__((address_space(3)))
#define AS1 __attribute__((address_space(1)))

__device__ __forceinline__ void gll16(const void* g, void* l) {
    __builtin_amdgcn_global_load_lds((const AS1 unsigned int*)g,
                                     (AS3 unsigned int*)l, 16, 0, 0);
}

__device__ __forceinline__ bf8 bf8_zero() {
    bf8 z;
#pragma unroll
    for (int i = 0; i < 8; i++) z[i] = (__bf16)0.0f;
    return z;
}

// ---------------- prep: embT + W1T + W2T + zero(h0f) ----------------
__global__ __launch_bounds__(256) void k_prep(const float* __restrict__ embed,
                                              const float* __restrict__ basis1,
                                              const float* __restrict__ att1,
                                              const float* __restrict__ basis2,
                                              const float* __restrict__ att2,
                                              __bf16* __restrict__ embT,
                                              __bf16* __restrict__ W1T,
                                              __bf16* __restrict__ W2T,
                                              float* __restrict__ h0f) {
    int b = blockIdx.x;
    if (b < 512) {
        int idx = b * 256 + threadIdx.x;        // embT[n][k] = embed[k][n]
        int n = idx >> 11, k = idx & 2047;
        embT[idx] = (__bf16)embed[k * NEMB + n];
    } else if (b < 576) {
        int r = b - 512;
        __shared__ float a[NB];
        if (threadIdx.x < NB) a[threadIdx.x] = att1[r * NB + threadIdx.x];
        __syncthreads();
        for (int idx = threadIdx.x; idx < NH1 * NEMB; idx += 256) {
            int o = idx >> 6, i = idx & 63;
            float acc = 0.f;
#pragma unroll
            for (int bb = 0; bb < NB; bb++) acc += a[bb] * basis1[(bb * NEMB + i) * NH1 + o];
            W1T[r * (NH1 * NEMB) + idx] = (__bf16)acc;
        }
    } else if (b < 640) {
        int r = b - 576;
        __shared__ float a[NB];
        if (threadIdx.x < NB) a[threadIdx.x] = att2[r * NB + threadIdx.x];
        __syncthreads();
        for (int idx = threadIdx.x; idx < NH2 * NH1; idx += 256) {
            int o = idx >> 5, i = idx & 31;
            float acc = 0.f;
#pragma unroll
            for (int bb = 0; bb < NB; bb++) acc += a[bb] * basis2[(bb * NH1 + i) * NH2 + o];
            W2T[r * (NH2 * NH1) + idx] = (__bf16)acc;
        }
    } else {
        // zero h0f: 470 blocks x 256 thr x 16 f4 = 1.925M f4 >= 480000... (exact cover)
        f4* p = (f4*)h0f;
        const int total = NN * NEMB / 4;             // 480,000 f4
        for (int i = (b - 640) * 256 + threadIdx.x; i < total; i += 470 * 256)
            p[i] = (f4)0.0f;
    }
}

// ---------------- K-split GEMM: r10 dbuf schedule, K=512/block, atomic h0f ----------------
// Grid 3752 = 938 row-tiles x 4 K-sections. Block: 32 rows x 64 cols x K=512.
__global__ __launch_bounds__(256) void k_gemm(const float* __restrict__ x,
                                              const __bf16* __restrict__ embT,
                                              float* __restrict__ h0f) {
    __shared__ __align__(16) float  As[2][32 * 128];    // 2 x 16,384 B
    __shared__ __align__(16) __bf16 Bs[2][64 * 128];    // 2 x 16,384 B
    int t = threadIdx.x;
    int wv = t >> 6, lane = t & 63;
    int l15 = lane & 15, kg = lane >> 4;
    int rowbase = (blockIdx.x >> 2) * 32;
    int c0 = (blockIdx.x & 3) * 4;                      // chunk base (4 chunks of 128)
    int half = lane >> 5;
    int bslot = lane & 31;
    int q16 = lane >> 4;
    int slot16 = lane & 15;
    int n = wv * 16 + l15;
    int nswz = (n & 7) << 4;
    int aswz = (l15 & 7) << 4;
    f4 acc0 = (f4)0.0f, acc1 = (f4)0.0f;

    auto STAGE = [&](int c, int buf) {
#pragma unroll
        for (int i = 0; i < 4; i++) {               // A: 4 gll (2 rows x 512B each)
            int rp = wv * 4 + i;
            int row = rp * 2 + half;
            int grow = rowbase + row;
            if (grow >= NN) grow = NN - 1;
            const char* g = (const char*)x + (size_t)grow * (IND * 4) + c * 512
                          + ((bslot * 16) ^ ((row & 7) << 4));
            gll16(g, (char*)&As[buf][0] + rp * 1024);
        }
#pragma unroll
        for (int i = 0; i < 4; i++) {               // B: 4 gll (4 rows x 256B each)
            int rp = wv * 4 + i;
            int row = rp * 4 + q16;
            const char* g = (const char*)embT + (size_t)row * (IND * 2) + c * 256
                          + ((slot16 * 16) ^ ((row & 7) << 4));
            gll16(g, (char*)&Bs[buf][0] + rp * 1024);
        }
    };

    STAGE(c0, 0);
#pragma unroll
    for (int ci = 0; ci < 4; ci++) {
        int buf = ci & 1;
        if (ci < 3) {
            STAGE(c0 + ci + 1, buf ^ 1);
            asm volatile("s_waitcnt vmcnt(8)" ::: "memory");
        } else {
            asm volatile("s_waitcnt vmcnt(0)" ::: "memory");
        }
        __builtin_amdgcn_s_barrier();
        __builtin_amdgcn_sched_barrier(0);
        const char* bsrow  = (const char*)&Bs[buf][0] + n * 256;
        const char* asrow0 = (const char*)&As[buf][0] + l15 * 512;
        const char* asrow1 = (const char*)&As[buf][0] + (l15 + 16) * 512;
#pragma unroll
        for (int kk = 0; kk < 4; kk++) {
            int aoff = ((kk * 128 + kg * 32) ^ aswz);
            float4 lo0 = *(const float4*)(asrow0 + aoff);
            float4 hi0 = *(const float4*)(asrow0 + (aoff ^ 16));
            float4 lo1 = *(const float4*)(asrow1 + aoff);
            float4 hi1 = *(const float4*)(asrow1 + (aoff ^ 16));
            bf8 b = *(const bf8*)(bsrow + ((kk * 64 + kg * 16) ^ nswz));
            bf8 a0, a1;
            a0[0]=(__bf16)lo0.x; a0[1]=(__bf16)lo0.y; a0[2]=(__bf16)lo0.z; a0[3]=(__bf16)lo0.w;
            a0[4]=(__bf16)hi0.x; a0[5]=(__bf16)hi0.y; a0[6]=(__bf16)hi0.z; a0[7]=(__bf16)hi0.w;
            a1[0]=(__bf16)lo1.x; a1[1]=(__bf16)lo1.y; a1[2]=(__bf16)lo1.z; a1[3]=(__bf16)lo1.w;
            a1[4]=(__bf16)hi1.x; a1[5]=(__bf16)hi1.y; a1[6]=(__bf16)hi1.z; a1[7]=(__bf16)hi1.w;
            acc0 = __builtin_amdgcn_mfma_f32_16x16x32_bf16(a0, b, acc0, 0, 0, 0);
            acc1 = __builtin_amdgcn_mfma_f32_16x16x32_bf16(a1, b, acc1, 0, 0, 0);
        }
        __builtin_amdgcn_sched_barrier(0);
        __builtin_amdgcn_s_barrier();
    }
    // ---- epilogue: fire-and-forget atomic accumulate into h0f ----
#pragma unroll
    for (int j = 0; j < 4; j++) {
        int r0 = rowbase + kg * 4 + j;
        int r1 = r0 + 16;
        if (r0 < NN) atomicAdd(h0f + (size_t)r0 * NEMB + n, acc0[j]);
        if (r1 < NN) atomicAdd(h0f + (size_t)r1 * NEMB + n, acc1[j]);
    }
}

// ---------------- init1h: h0f -> h0b (bf16, /xnorm) + out1 = bias1 + h0 @ root1 ----------------
__global__ __launch_bounds__(256) void k_init1h(const float* __restrict__ h0f,
                                                const float* __restrict__ xnorm,
                                                const float* __restrict__ root1,
                                                const float* __restrict__ bias1,
                                                __bf16* __restrict__ h0b,
                                                float* __restrict__ out1) {
    int t = threadIdx.x;
    int row = blockIdx.x * 16 + (t >> 4);        // 1875 blocks exact
    int tc = t & 15;
    float inv = 1.0f / xnorm[row];
    const float* hr = h0f + (size_t)row * NEMB;
    float h[NEMB];
#pragma unroll
    for (int k4 = 0; k4 < 16; k4++) {
        float4 v = *(const float4*)(hr + k4 * 4);
        h[k4 * 4 + 0] = v.x * inv;
        h[k4 * 4 + 1] = v.y * inv;
        h[k4 * 4 + 2] = v.z * inv;
        h[k4 * 4 + 3] = v.w * inv;
    }
    // h0b write: this thread's 4 cols
    bf4 hb;
#pragma unroll
    for (int j = 0; j < 4; j++) hb[j] = (__bf16)h[tc * 4 + j];
    *(bf4*)(h0b + (size_t)row * NEMB + tc * 4) = hb;
    // out1 GEMV: cols 2*tc, 2*tc+1
    int colp = tc * 2;
    float ax = bias1[colp], ay = bias1[colp + 1];
#pragma unroll
    for (int k = 0; k < NEMB; k++) {
        const float* w = root1 + k * NH1 + colp;
        ax += h[k] * w[0];
        ay += h[k] * w[1];
    }
    float2 o; o.x = ax; o.y = ay;
    *(float2*)(out1 + (size_t)row * NH1 + colp) = o;
}

// ---------------- edge layer 1 (r10 verbatim): atomic scatter ----------------
__global__ __launch_bounds__(256) void k_edge1(const int* __restrict__ ei,
                                               const int* __restrict__ et,
                                               const __bf16* __restrict__ h0b,
                                               const __bf16* __restrict__ W1T,
                                               float* __restrict__ out1) {
    int wave = threadIdx.x >> 6, lane = threadIdx.x & 63;
    int l15 = lane & 15, kg = lane >> 4;
    int wid = blockIdx.x * 4 + wave;             // 30000 waves, 32 edges each
    int er0 = wid * 32 + l15, er1 = er0 + 16;
    int et0v = et[er0],  et1v = et[er1];
    int src0 = ei[er0],  src1 = ei[er1];
    int dst0 = ei[EE + er0], dst1 = ei[EE + er1];
    const __bf16* hp0 = h0b + (size_t)src0 * NEMB + kg * 8;
    const __bf16* hp1 = h0b + (size_t)src1 * NEMB + kg * 8;
    bf8 a00 = *(const bf8*)hp0;
    bf8 a01 = *(const bf8*)(hp0 + 32);
    bf8 a10 = *(const bf8*)hp1;
    bf8 a11 = *(const bf8*)(hp1 + 32);
    bf8 zero = bf8_zero();
#pragma unroll
    for (int b = 0; b < 2; b++) {
        int my_et = b ? et1v : et0v;
        int my_dst = b ? dst1 : dst0;
        bf8 a0 = b ? a10 : a00;
        bf8 a1 = b ? a11 : a01;
        f4 c0 = (f4)0.0f, c1 = (f4)0.0f;
        int pos = 0;
        while (pos < 16) {
            int r = __shfl(my_et, pos);
            unsigned long long bl = __ballot(my_et == r);
            unsigned m16 = (unsigned)(bl & 0xFFFFull);
            int run = __builtin_ctz(~(m16 >> pos));
            int end = pos + run;
            const __bf16* wb = W1T + (size_t)r * (NH1 * NEMB) + (size_t)l15 * NEMB + kg * 8;
            bf8 b00 = *(const bf8*)(wb);
            bf8 b01 = *(const bf8*)(wb + 32);
            bf8 b10 = *(const bf8*)(wb + 16 * NEMB);
            bf8 b11 = *(const bf8*)(wb + 16 * NEMB + 32);
            bool use = (l15 >= pos) && (l15 < end);
            bf8 ua0 = use ? a0 : zero;
            bf8 ua1 = use ? a1 : zero;
            c0 = __builtin_amdgcn_mfma_f32_16x16x32_bf16(ua0, b00, c0, 0, 0, 0);
            c0 = __builtin_amdgcn_mfma_f32_16x16x32_bf16(ua1, b01, c0, 0, 0, 0);
            c1 = __builtin_amdgcn_mfma_f32_16x16x32_bf16(ua0, b10, c1, 0, 0, 0);
            c1 = __builtin_amdgcn_mfma_f32_16x16x32_bf16(ua1, b11, c1, 0, 0, 0);
            pos = end;
        }
#pragma unroll
        for (int j = 0; j < 4; j++) {
            int eidx = kg * 4 + j;               // C row = edge index in batch
            int dst = __shfl(my_dst, eidx);
            atomicAdd(out1 + (size_t)dst * NH1 + l15,      c0[j]);
            atomicAdd(out1 + (size_t)dst * NH1 + 16 + l15, c1[j]);
        }
    }
}

// ---------------- mid (r10 verbatim): relu -> h1b AND out = bias2 + h1 @ root2 ----------------
__global__ __launch_bounds__(256) void k_mid(const float* __restrict__ out1,
                                             const float* __restrict__ root2,
                                             const float* __restrict__ bias2,
                                             __bf16* __restrict__ h1b,
                                             float* __restrict__ out) {
    int t = threadIdx.x;
    int row = blockIdx.x * 16 + (t >> 4);        // 1875 blocks exact
    int col = t & 15;
    const float* orow = out1 + (size_t)row * NH1;
    float h[NH1];
#pragma unroll
    for (int k = 0; k < NH1; k++) h[k] = fmaxf(orow[k], 0.f);
    bf2 hb;
    hb[0] = (__bf16)h[2 * col];
    hb[1] = (__bf16)h[2 * col + 1];
    *(bf2*)(h1b + (size_t)row * NH1 + 2 * col) = hb;
    float acc = bias2[col];
#pragma unroll
    for (int k = 0; k < NH1; k++) acc += h[k] * root2[k * NH2 + col];
    out[(size_t)row * NH2 + col] = acc;
}

// ---------------- edge layer 2 (r10 verbatim): atomic scatter ----------------
__global__ __launch_bounds__(256) void k_edge2(const int* __restrict__ ei,
                                               const int* __restrict__ et,
                                               const __bf16* __restrict__ h1b,
                                               const __bf16* __restrict__ W2T,
                                               float* __restrict__ out) {
    int wave = threadIdx.x >> 6, lane = threadIdx.x & 63;
    int l15 = lane & 15, kg = lane >> 4;
    int wid = blockIdx.x * 4 + wave;
    int er0 = wid * 32 + l15, er1 = er0 + 16;
    int et0v = et[er0],  et1v = et[er1];
    int src0 = ei[er0],  src1 = ei[er1];
    int dst0 = ei[EE + er0], dst1 = ei[EE + er1];
    bf8 ab0 = *(const bf8*)(h1b + (size_t)src0 * NH1 + kg * 8);
    bf8 ab1 = *(const bf8*)(h1b + (size_t)src1 * NH1 + kg * 8);
    bf8 zero = bf8_zero();
#pragma unroll
    for (int b = 0; b < 2; b++) {
        int my_et = b ? et1v : et0v;
        int my_dst = b ? dst1 : dst0;
        bf8 a = b ? ab1 : ab0;
        f4 c = (f4)0.0f;
        int pos = 0;
        while (pos < 16) {
            int r = __shfl(my_et, pos);
            unsigned long long bl = __ballot(my_et == r);
            unsigned m16 = (unsigned)(bl & 0xFFFFull);
            int run = __builtin_ctz(~(m16 >> pos));
            int end = pos + run;
            bf8 bb = *(const bf8*)(W2T + (size_t)r * (NH2 * NH1) + (size_t)l15 * NH1 + kg * 8);
            bool use = (l15 >= pos) && (l15 < end);
            c = __builtin_amdgcn_mfma_f32_16x16x32_bf16(use ? a : zero, bb, c, 0, 0, 0);
            pos = end;
        }
#pragma unroll
        for (int j = 0; j < 4; j++) {
            int eidx = kg * 4 + j;
            int dst = __shfl(my_dst, eidx);
            atomicAdd(out + (size_t)dst * NH2 + l15, c[j]);
        }
    }
}

// ---------------- relu2 (in place on d_out) ----------------
__global__ __launch_bounds__(256) void k_relu2(float* __restrict__ o) {
    int i = blockIdx.x * 256 + threadIdx.x;
    if (i >= NN * NH2 / 4) return;
    float4 v = ((float4*)o)[i];
    v.x = fmaxf(v.x, 0.f); v.y = fmaxf(v.y, 0.f);
    v.z = fmaxf(v.z, 0.f); v.w = fmaxf(v.w, 0.f);
    ((float4*)o)[i] = v;
}

// ---------------- launch ----------------
extern "C" void kernel_launch(void* const* d_in, const int* in_sizes, int n_in,
                              void* d_out, int out_size, void* d_ws, size_t ws_size,
                              hipStream_t stream) {
    const float* x      = (const float*)d_in[0];
    const int*   ei     = (const int*)d_in[1];
    const int*   et     = (const int*)d_in[2];
    const float* xnorm  = (const float*)d_in[4];
    const float* embed  = (const float*)d_in[5];
    const float* basis1 = (const float*)d_in[6];
    const float* att1   = (const float*)d_in[7];
    const float* root1  = (const float*)d_in[8];
    const float* bias1  = (const float*)d_in[9];
    const float* basis2 = (const float*)d_in[10];
    const float* att2   = (const float*)d_in[11];
    const float* root2  = (const float*)d_in[12];
    const float* bias2  = (const float*)d_in[13];
    float* out = (float*)d_out;

    char* ws = (char*)d_ws;
    __bf16* embT = (__bf16*)(ws + 0);              //   262,144
    __bf16* W1T  = (__bf16*)(ws + 262144);         //   262,144
    __bf16* W2T  = (__bf16*)(ws + 524288);         //    65,536
    __bf16* h0b  = (__bf16*)(ws + 589824);         // 3,840,000
    float*  out1 = (float*) (ws + 4429824);        // 3,840,000
    __bf16* h1b  = (__bf16*)(ws + 8269824);        // 1,920,000
    float*  h0f  = (float*) (ws + 10189824);       // 7,680,000  (end ~17.9 MB)

    k_prep  <<<1110, 256, 0, stream>>>(embed, basis1, att1, basis2, att2,
                                       embT, W1T, W2T, h0f);
    k_gemm  <<<3752, 256, 0, stream>>>(x, embT, h0f);
    k_init1h<<<1875, 256, 0, stream>>>(h0f, xnorm, root1, bias1, h0b, out1);
    k_edge1 <<<7500, 256, 0, stream>>>(ei, et, h0b, W1T, out1);
    k_mid   <<<1875, 256, 0, stream>>>(out1, root2, bias2, h1b, out);
    k_edge2 <<<7500, 256, 0, stream>>>(ei, et, h1b, W2T, out);
    k_relu2 <<<469,  256, 0, stream>>>(out);
}